// Round 1
// baseline (338.604 us; speedup 1.0000x reference)
//
#include <hip/hip_runtime.h>
#include <hip/hip_bf16.h>
#include <cstdint>

#define B_ 128
#define T_ 500
#define M_ 512
#define L_ 128

typedef float  f32x4  __attribute__((ext_vector_type(4)));
typedef __bf16 bf16x8 __attribute__((ext_vector_type(8)));

__device__ __forceinline__ uint16_t f2bf(float f) {
  uint32_t u = __float_as_uint(f);
  u += 0x7FFFu + ((u >> 16) & 1u);   // round-to-nearest-even
  return (uint16_t)(u >> 16);
}

// K1: convert Wv,Wu [M,L] f32 -> transposed bf16 [2][L][M] in ws
__global__ void k_wconv(const float* __restrict__ Wv, const float* __restrict__ Wu,
                        uint16_t* __restrict__ Wb) {
  int id = blockIdx.x * 256 + threadIdx.x;   // 0..131071
  int w = id >> 16;
  int r = id & 65535;
  int l = r >> 9;
  int m = r & 511;
  const float* src = w ? Wu : Wv;
  Wb[(w << 16) + l * 512 + m] = f2bf(src[m * 128 + l]);
}

// K2: per (bag, 128-t tile): bf16 MFMA gates GEMM + gated logit -> At
__launch_bounds__(256)
__global__ void k_gates(const float* __restrict__ H, const uint16_t* __restrict__ Wb,
                        const float* __restrict__ bv, const float* __restrict__ bu,
                        const float* __restrict__ Wa, const float* __restrict__ ba,
                        float* __restrict__ At) {
  // LDS: Ht[128t][64k] bf16 @0, WvT[128l][64k] @8192, WuT @16384 (ushort idx)
  __shared__ __align__(16) uint16_t sm[24576];
  const int tid  = threadIdx.x;
  const int lane = tid & 63;
  const int wid  = tid >> 6;
  const int b     = blockIdx.y;
  const int tbase = blockIdx.x * 128;

  f32x4 accV[2][8], accU[2][8];
  #pragma unroll
  for (int i = 0; i < 2; ++i)
    #pragma unroll
    for (int j = 0; j < 8; ++j) {
      accV[i][j] = f32x4{0.f, 0.f, 0.f, 0.f};
      accU[i][j] = f32x4{0.f, 0.f, 0.f, 0.f};
    }

  const int lc = lane & 15;   // col-in-frag (L dim for B/C)
  const int kq = lane >> 4;   // k-quad

  for (int ks = 0; ks < 8; ++ks) {   // K = M = 512, 64 per step
    // stage Ht (f32 -> bf16, swizzled: 16B-chunk ^= (row&7))
    #pragma unroll
    for (int it = 0; it < 4; ++it) {
      int r  = it * 32 + (tid >> 3);
      int kc = tid & 7;
      float4 f0 = make_float4(0.f, 0.f, 0.f, 0.f), f1 = f0;
      int t = tbase + r;
      if (t < T_) {
        const float* src = H + ((size_t)b * T_ + t) * M_ + ks * 64 + kc * 8;
        f0 = *(const float4*)src;
        f1 = *(const float4*)(src + 4);
      }
      uint4 u;
      u.x = (uint32_t)f2bf(f0.x) | ((uint32_t)f2bf(f0.y) << 16);
      u.y = (uint32_t)f2bf(f0.z) | ((uint32_t)f2bf(f0.w) << 16);
      u.z = (uint32_t)f2bf(f1.x) | ((uint32_t)f2bf(f1.y) << 16);
      u.w = (uint32_t)f2bf(f1.z) | ((uint32_t)f2bf(f1.w) << 16);
      *(uint4*)&sm[r * 64 + ((kc ^ (r & 7)) << 3)] = u;
    }
    // stage WvT / WuT tiles (already bf16 in ws)
    #pragma unroll
    for (int it = 0; it < 4; ++it) {
      int c = it * 256 + tid;      // 0..1023 chunks of 16B
      int l = c >> 3, kc = c & 7;
      const uint4* gv = (const uint4*)&Wb[l * 512 + ks * 64 + kc * 8];
      const uint4* gu = (const uint4*)&Wb[65536 + l * 512 + ks * 64 + kc * 8];
      int dst = l * 64 + ((kc ^ (l & 7)) << 3);
      *(uint4*)&sm[8192 + dst]  = *gv;
      *(uint4*)&sm[16384 + dst] = *gu;
    }
    __syncthreads();
    #pragma unroll
    for (int kf = 0; kf < 2; ++kf) {
      const int kc = kf * 4 + kq;
      bf16x8 a0, a1;
      { int t0 = wid * 32 + lc;      a0 = *(const bf16x8*)&sm[t0 * 64 + ((kc ^ (t0 & 7)) << 3)]; }
      { int t1 = wid * 32 + 16 + lc; a1 = *(const bf16x8*)&sm[t1 * 64 + ((kc ^ (t1 & 7)) << 3)]; }
      #pragma unroll
      for (int lf = 0; lf < 8; ++lf) {
        int lr  = lf * 16 + lc;
        int off = lr * 64 + ((kc ^ (lr & 7)) << 3);
        bf16x8 bvf = *(const bf16x8*)&sm[8192 + off];
        bf16x8 buf = *(const bf16x8*)&sm[16384 + off];
        accV[0][lf] = __builtin_amdgcn_mfma_f32_16x16x32_bf16(a0, bvf, accV[0][lf], 0, 0, 0);
        accV[1][lf] = __builtin_amdgcn_mfma_f32_16x16x32_bf16(a1, bvf, accV[1][lf], 0, 0, 0);
        accU[0][lf] = __builtin_amdgcn_mfma_f32_16x16x32_bf16(a0, buf, accU[0][lf], 0, 0, 0);
        accU[1][lf] = __builtin_amdgcn_mfma_f32_16x16x32_bf16(a1, buf, accU[1][lf], 0, 0, 0);
      }
    }
    __syncthreads();
  }

  // epilogue: tanh(vg)*sigmoid(ug)*Wa, reduce over L, write logits
  float wa[8], bvv[8], buu[8];
  #pragma unroll
  for (int j = 0; j < 8; ++j) {
    int l = j * 16 + lc;
    wa[j] = Wa[l]; bvv[j] = bv[l]; buu[j] = bu[l];
  }
  float ba0 = ba[0];
  #pragma unroll
  for (int tf = 0; tf < 2; ++tf) {
    float part[4] = {0.f, 0.f, 0.f, 0.f};
    #pragma unroll
    for (int lf = 0; lf < 8; ++lf) {
      #pragma unroll
      for (int r = 0; r < 4; ++r) {
        float xv = accV[tf][lf][r] + bvv[lf];
        float xu = accU[tf][lf][r] + buu[lf];
        xv = fminf(fmaxf(xv, -30.f), 30.f);
        float e  = __expf(2.f * xv);
        float th = (e - 1.f) * __builtin_amdgcn_rcpf(e + 1.f);
        float sg = __builtin_amdgcn_rcpf(1.f + __expf(-xu));
        part[r] += th * sg * wa[lf];
      }
    }
    #pragma unroll
    for (int r = 0; r < 4; ++r) {
      part[r] += __shfl_xor(part[r], 1);
      part[r] += __shfl_xor(part[r], 2);
      part[r] += __shfl_xor(part[r], 4);
      part[r] += __shfl_xor(part[r], 8);
    }
    if (lc == 0) {
      #pragma unroll
      for (int r = 0; r < 4; ++r) {
        int t = tbase + wid * 32 + tf * 16 + kq * 4 + r;
        if (t < T_) At[b * T_ + t] = part[r] + ba0;
      }
    }
  }
}

// K3a: per-bag softmax over T=500
__global__ void k_softmax(const float* __restrict__ At, float* __restrict__ Asm) {
  __shared__ float red[8];
  const int b = blockIdx.x;
  const int tid = threadIdx.x;          // 512
  const int lane = tid & 63, wid = tid >> 6;
  float x0 = (tid < T_) ? At[b * T_ + tid] : -3.4e38f;
  float x = x0;
  #pragma unroll
  for (int m = 32; m; m >>= 1) x = fmaxf(x, __shfl_xor(x, m));
  if (lane == 0) red[wid] = x;
  __syncthreads();
  float mx = red[0];
  #pragma unroll
  for (int w = 1; w < 8; ++w) mx = fmaxf(mx, red[w]);
  float e = (tid < T_) ? __expf(x0 - mx) : 0.f;
  float s = e;
  #pragma unroll
  for (int m = 32; m; m >>= 1) s += __shfl_xor(s, m);
  __syncthreads();
  if (lane == 0) red[wid] = s;
  __syncthreads();
  float tot = 0.f;
  #pragma unroll
  for (int w = 0; w < 8; ++w) tot += red[w];
  if (tid < T_) Asm[b * T_ + tid] = e / tot;
}

// K3b: Mpool[b,m] = sum_t s[t] * H[b,t,m]   (grid: 4 m-chunks x 128 bags)
__global__ void k_pool(const float* __restrict__ H, const float* __restrict__ Asm,
                       float* __restrict__ Mp) {
  __shared__ float sv[T_];
  __shared__ float red[128];
  const int tid = threadIdx.x;  // 256
  const int b = blockIdx.y, mc = blockIdx.x;
  for (int i = tid; i < T_; i += 256) sv[i] = Asm[b * T_ + i];
  __syncthreads();
  const int m = mc * 128 + (tid & 127);
  const int half = tid >> 7;
  const float* hp = H + (size_t)b * T_ * M_ + m;
  float acc = 0.f;
  for (int t = half; t < T_; t += 2) acc += sv[t] * hp[(size_t)t * M_];
  if (half) red[tid & 127] = acc;
  __syncthreads();
  if (!half) Mp[b * 512 + m] = acc + red[tid & 127];
}

// K4: out[b,:] = Mpool[b,:] @ Wc + bc
__global__ void k_head(const float* __restrict__ Mp, const float* __restrict__ Wc,
                       const float* __restrict__ bc, float* __restrict__ out) {
  const int b = blockIdx.x;
  const int lane = threadIdx.x;  // 64
  float a0 = 0.f, a1 = 0.f;
  for (int i = lane; i < 512; i += 64) {
    float p = Mp[b * 512 + i];
    a0 += p * Wc[i * 2];
    a1 += p * Wc[i * 2 + 1];
  }
  #pragma unroll
  for (int m = 32; m; m >>= 1) { a0 += __shfl_xor(a0, m); a1 += __shfl_xor(a1, m); }
  if (lane == 0) { out[b * 2] = a0 + bc[0]; out[b * 2 + 1] = a1 + bc[1]; }
}

extern "C" void kernel_launch(void* const* d_in, const int* in_sizes, int n_in,
                              void* d_out, int out_size, void* d_ws, size_t ws_size,
                              hipStream_t stream) {
  const float* H  = (const float*)d_in[0];
  const float* Wv = (const float*)d_in[1];
  const float* bv = (const float*)d_in[2];
  const float* Wu = (const float*)d_in[3];
  const float* bu = (const float*)d_in[4];
  const float* Wa = (const float*)d_in[5];
  const float* ba = (const float*)d_in[6];
  const float* Wc = (const float*)d_in[7];
  const float* bc = (const float*)d_in[8];

  float* out = (float*)d_out;                   // [128,2]
  float* Asm = out + 256;                       // [128,500] A_after_sftmx
  float* At  = out + 256 + 64000;               // [128,500] A_t (logits)

  uint16_t* Wb = (uint16_t*)d_ws;               // 2 x [128][512] bf16 = 256KB
  float* Mp = (float*)((char*)d_ws + 262144);   // [128][512] f32 = 256KB

  hipLaunchKernelGGL(k_wconv,   dim3(512),     dim3(256), 0, stream, Wv, Wu, Wb);
  hipLaunchKernelGGL(k_gates,   dim3(4, 128),  dim3(256), 0, stream, H, Wb, bv, bu, Wa, ba, At);
  hipLaunchKernelGGL(k_softmax, dim3(128),     dim3(512), 0, stream, At, Asm);
  hipLaunchKernelGGL(k_pool,    dim3(4, 128),  dim3(256), 0, stream, H, Asm, Mp);
  hipLaunchKernelGGL(k_head,    dim3(128),     dim3(64),  0, stream, Mp, Wc, bc, out);
}

// Round 2
// 243.732 us; speedup vs baseline: 1.3892x; 1.3892x over previous
//
#include <hip/hip_runtime.h>
#include <hip/hip_bf16.h>
#include <cstdint>

#define B_ 128
#define T_ 500
#define M_ 512
#define L_ 128
#define NTILE 8   // ceil(500/64)

typedef float  f32x4  __attribute__((ext_vector_type(4)));
typedef __bf16 bf16x8 __attribute__((ext_vector_type(8)));

__device__ __forceinline__ uint32_t f2bf(float f) {
  uint32_t u = __float_as_uint(f);
  u += 0x7FFFu + ((u >> 16) & 1u);   // round-to-nearest-even
  return u >> 16;
}

__device__ __forceinline__ void gld_lds16(const uint16_t* g, uint16_t* l) {
  __builtin_amdgcn_global_load_lds((const __attribute__((address_space(1))) uint32_t*)g,
                                   (__attribute__((address_space(3))) uint32_t*)l,
                                   16, 0, 0);
}

// K1: convert Wv,Wu [M,L] f32 -> transposed bf16 [2][L][M] in ws
__global__ void k_wconv(const float* __restrict__ Wv, const float* __restrict__ Wu,
                        uint16_t* __restrict__ Wb) {
  int id = blockIdx.x * 256 + threadIdx.x;   // 0..131071
  int w = id >> 16;
  int r = id & 65535;
  int l = r >> 9;
  int m = r & 511;
  const float* src = w ? Wu : Wv;
  Wb[(w << 16) + l * 512 + m] = (uint16_t)f2bf(src[m * 128 + l]);
}

// K2: fused gates GEMM (bf16 MFMA) + logits + e_t + tile-local pooling.
// grid (NTILE, B_), 256 threads = 4 waves x 16 t-rows each.
__global__ __launch_bounds__(256)
void k_gates_pool(const float* __restrict__ H, const uint16_t* __restrict__ Wb,
                  const float* __restrict__ bv, const float* __restrict__ bu,
                  const float* __restrict__ Wa, const float* __restrict__ ba,
                  float* __restrict__ At, float* __restrict__ Ew,
                  float* __restrict__ Sums, float* __restrict__ Mp8) {
  // LDS (ushort idx): W[2 buf][2 g][128 L][32 k] = 16384 ; H[2 buf][64 t][32 k] = 4096
  __shared__ __align__(16) uint16_t sm[20480];
  __shared__ float esm[64];
  const int tid  = threadIdx.x;
  const int lane = tid & 63;
  const int wv   = tid >> 6;
  const int lc   = lane & 15;
  const int kq   = lane >> 4;
  const int tile  = blockIdx.x;
  const int b     = blockIdx.y;
  const int tbase = tile * 64;

  // H staging: thread owns row ht = tid>>2, chunk hcc = tid&3 (8 f32)
  const int ht  = tid >> 2;
  const int hcc = tid & 3;
  const int gts = tbase + ht;
  const bool hv = (gts < T_);
  const float* hsrc = H + ((size_t)b * T_ + (hv ? gts : 0)) * M_ + hcc * 8;

  f32x4 accV[8], accU[8];
  #pragma unroll
  for (int i = 0; i < 8; ++i) { accV[i] = f32x4{0.f,0.f,0.f,0.f}; accU[i] = f32x4{0.f,0.f,0.f,0.f}; }

  float hf[8];

  // ---- prologue: stage ks=0 into buf 0
  #pragma unroll
  for (int j = 0; j < 4; ++j) {
    int i = j * 256 + tid;
    gld_lds16(Wb + ((i >> 9) << 16) + (((i >> 2) & 127) << 9) + ((i & 3) << 3),
              &sm[i * 8]);
  }
  {
    float4 p0 = make_float4(0.f,0.f,0.f,0.f), p1 = p0;
    if (hv) { p0 = *(const float4*)(hsrc); p1 = *(const float4*)(hsrc + 4); }
    uint4 u;
    u.x = f2bf(p0.x) | (f2bf(p0.y) << 16);
    u.y = f2bf(p0.z) | (f2bf(p0.w) << 16);
    u.z = f2bf(p1.x) | (f2bf(p1.y) << 16);
    u.w = f2bf(p1.z) | (f2bf(p1.w) << 16);
    *(uint4*)&sm[16384 + ht * 32 + hcc * 8] = u;
  }
  __syncthreads();

  int buf = 0;
  for (int s = 0; s < 16; ++s) {          // K = 512, 32 per step
    if (s < 15) {
      const int ks = s + 1;
      #pragma unroll
      for (int j = 0; j < 4; ++j) {
        int i = j * 256 + tid;
        gld_lds16(Wb + ((i >> 9) << 16) + (((i >> 2) & 127) << 9) + (ks << 5) + ((i & 3) << 3),
                  &sm[(buf ^ 1) * 8192 + i * 8]);
      }
      float4 p0 = make_float4(0.f,0.f,0.f,0.f), p1 = p0;
      if (hv) { p0 = *(const float4*)(hsrc + ks * 32); p1 = *(const float4*)(hsrc + ks * 32 + 4); }
      hf[0]=p0.x; hf[1]=p0.y; hf[2]=p0.z; hf[3]=p0.w;
      hf[4]=p1.x; hf[5]=p1.y; hf[6]=p1.z; hf[7]=p1.w;
    }
    // compute current buffer
    {
      const uint16_t* Hb = &sm[16384 + buf * 2048];
      const uint16_t* Wp = &sm[buf * 8192];
      bf16x8 a = *(const bf16x8*)&Hb[(wv * 16 + lc) * 32 + kq * 8];
      #pragma unroll
      for (int lf = 0; lf < 8; ++lf) {
        int off = (lf * 16 + lc) * 32 + kq * 8;
        bf16x8 bw = *(const bf16x8*)&Wp[off];
        bf16x8 uw = *(const bf16x8*)&Wp[4096 + off];
        accV[lf] = __builtin_amdgcn_mfma_f32_16x16x32_bf16(a, bw, accV[lf], 0, 0, 0);
        accU[lf] = __builtin_amdgcn_mfma_f32_16x16x32_bf16(a, uw, accU[lf], 0, 0, 0);
      }
    }
    if (s < 15) {
      uint4 u;
      u.x = f2bf(hf[0]) | (f2bf(hf[1]) << 16);
      u.y = f2bf(hf[2]) | (f2bf(hf[3]) << 16);
      u.z = f2bf(hf[4]) | (f2bf(hf[5]) << 16);
      u.w = f2bf(hf[6]) | (f2bf(hf[7]) << 16);
      *(uint4*)&sm[16384 + (buf ^ 1) * 2048 + ht * 32 + hcc * 8] = u;
    }
    __syncthreads();
    buf ^= 1;
  }

  // ---- epilogue: gated logit, e_t, tile partial sum
  float wa[8], bvv[8], buu[8];
  #pragma unroll
  for (int j = 0; j < 8; ++j) {
    int l = j * 16 + lc;
    wa[j] = Wa[l]; bvv[j] = bv[l]; buu[j] = bu[l];
  }
  float ba0 = ba[0];
  float part[4] = {0.f, 0.f, 0.f, 0.f};
  #pragma unroll
  for (int lf = 0; lf < 8; ++lf) {
    #pragma unroll
    for (int r = 0; r < 4; ++r) {
      float xv = accV[lf][r] + bvv[lf];
      float xu = accU[lf][r] + buu[lf];
      xv = fminf(fmaxf(xv, -30.f), 30.f);
      float e  = __expf(2.f * xv);
      float th = (e - 1.f) * __builtin_amdgcn_rcpf(e + 1.f);
      float sg = __builtin_amdgcn_rcpf(1.f + __expf(-xu));
      part[r] += th * sg * wa[lf];
    }
  }
  #pragma unroll
  for (int r = 0; r < 4; ++r) {
    part[r] += __shfl_xor(part[r], 1);
    part[r] += __shfl_xor(part[r], 2);
    part[r] += __shfl_xor(part[r], 4);
    part[r] += __shfl_xor(part[r], 8);
  }
  if (lc == 0) {
    #pragma unroll
    for (int r = 0; r < 4; ++r) {
      int tl = wv * 16 + kq * 4 + r;
      int gt = tbase + tl;
      float logit = part[r] + ba0;
      float e = 0.f;
      if (gt < T_) {
        At[b * T_ + gt] = logit;
        e = __expf(logit);               // no max-subtraction: |logit| small
        Ew[(b << 9) + gt] = e;
      }
      esm[tl] = e;
    }
  }
  __syncthreads();
  if (tid < 64) {
    float v = esm[tid];
    v += __shfl_xor(v, 1);  v += __shfl_xor(v, 2);  v += __shfl_xor(v, 4);
    v += __shfl_xor(v, 8);  v += __shfl_xor(v, 16); v += __shfl_xor(v, 32);
    if (tid == 0) Sums[b * NTILE + tile] = v;
  }

  // ---- pooling: P[m] = sum_t e_t * H[t,m] for this tile (H re-read is L3-hot)
  const int tmax = min(64, T_ - tbase);
  const float* hp = H + ((size_t)b * T_ + tbase) * M_;
  float a0 = 0.f, a1 = 0.f;
  for (int t = 0; t < tmax; ++t) {
    float e = esm[t];
    a0 += e * hp[(size_t)t * M_ + tid];
    a1 += e * hp[(size_t)t * M_ + tid + 256];
  }
  float* mp = Mp8 + ((size_t)(b * NTILE + tile) << 9);
  mp[tid]       = a0;
  mp[tid + 256] = a1;
}

// K3: per-bag finish: sum-e, A_sm normalize, Mpool reduce, head GEMV
__global__ void k_finish(const float* __restrict__ Ew, const float* __restrict__ Sums,
                         const float* __restrict__ Mp8, const float* __restrict__ Wc,
                         const float* __restrict__ bc, float* __restrict__ out,
                         float* __restrict__ Asm) {
  __shared__ float rs[8];
  const int b = blockIdx.x;
  const int tid = threadIdx.x;
  float se = 0.f;
  #pragma unroll
  for (int j = 0; j < NTILE; ++j) se += Sums[b * NTILE + j];
  const float inv = 1.f / se;
  for (int t = tid; t < T_; t += 256) Asm[b * T_ + t] = Ew[(b << 9) + t] * inv;
  float mp0 = 0.f, mp1 = 0.f;
  #pragma unroll
  for (int j = 0; j < NTILE; ++j) {
    const float* mp = Mp8 + ((size_t)(b * NTILE + j) << 9);
    mp0 += mp[tid];
    mp1 += mp[tid + 256];
  }
  mp0 *= inv; mp1 *= inv;
  float c0 = mp0 * Wc[tid * 2]     + mp1 * Wc[(tid + 256) * 2];
  float c1 = mp0 * Wc[tid * 2 + 1] + mp1 * Wc[(tid + 256) * 2 + 1];
  #pragma unroll
  for (int m = 32; m; m >>= 1) { c0 += __shfl_xor(c0, m); c1 += __shfl_xor(c1, m); }
  const int lane = tid & 63, wv = tid >> 6;
  if (lane == 0) { rs[wv] = c0; rs[4 + wv] = c1; }
  __syncthreads();
  if (tid == 0) out[b * 2]     = rs[0] + rs[1] + rs[2] + rs[3] + bc[0];
  if (tid == 1) out[b * 2 + 1] = rs[4] + rs[5] + rs[6] + rs[7] + bc[1];
}

extern "C" void kernel_launch(void* const* d_in, const int* in_sizes, int n_in,
                              void* d_out, int out_size, void* d_ws, size_t ws_size,
                              hipStream_t stream) {
  const float* H  = (const float*)d_in[0];
  const float* Wv = (const float*)d_in[1];
  const float* bv = (const float*)d_in[2];
  const float* Wu = (const float*)d_in[3];
  const float* bu = (const float*)d_in[4];
  const float* Wa = (const float*)d_in[5];
  const float* ba = (const float*)d_in[6];
  const float* Wc = (const float*)d_in[7];
  const float* bc = (const float*)d_in[8];

  float* out = (float*)d_out;                   // [128,2]
  float* Asm = out + 256;                       // [128,500] A_after_sftmx
  float* At  = out + 256 + 64000;               // [128,500] A_t (logits)

  uint16_t* Wb = (uint16_t*)d_ws;                        // 2 x [128][512] bf16 = 256 KB
  float* Ew   = (float*)((char*)d_ws + 262144);          // [128][512] f32 = 256 KB
  float* Sums = (float*)((char*)d_ws + 524288);          // [128][8]       = 4 KB
  float* Mp8  = (float*)((char*)d_ws + 528384);          // [128][8][512]  = 2 MB

  hipLaunchKernelGGL(k_wconv,      dim3(512),          dim3(256), 0, stream, Wv, Wu, Wb);
  hipLaunchKernelGGL(k_gates_pool, dim3(NTILE, B_),    dim3(256), 0, stream,
                     H, Wb, bv, bu, Wa, ba, At, Ew, Sums, Mp8);
  hipLaunchKernelGGL(k_finish,     dim3(B_),           dim3(256), 0, stream,
                     Ew, Sums, Mp8, Wc, bc, out, Asm);
}

// Round 4
// 230.309 us; speedup vs baseline: 1.4702x; 1.0583x over previous
//
#include <hip/hip_runtime.h>
#include <hip/hip_bf16.h>
#include <cstdint>

#define B_ 128
#define T_ 500
#define M_ 512
#define L_ 128
#define NTILE 8   // ceil(500/64)

typedef float  f32x4  __attribute__((ext_vector_type(4)));
typedef __bf16 bf16x8 __attribute__((ext_vector_type(8)));

__device__ __forceinline__ uint32_t f2bf(float f) {
  uint32_t u = __float_as_uint(f);
  u += 0x7FFFu + ((u >> 16) & 1u);   // round-to-nearest-even
  return u >> 16;
}

__device__ __forceinline__ void gld_lds16(const uint16_t* g, uint16_t* l) {
  __builtin_amdgcn_global_load_lds((const __attribute__((address_space(1))) uint32_t*)g,
                                   (__attribute__((address_space(3))) uint32_t*)l,
                                   16, 0, 0);
}

// K1: transpose+convert+PRE-SWIZZLE Wv,Wu [M,L] f32 -> Wb[g][l][ks][c][e] bf16
// stored so that Wb[g][l][ks][c][e] = W_g[ ks*32 + (c ^ ((l>>1)&3))*8 + e, l ].
// Then the gates kernel's global_load_lds source is LINEAR and the LDS content
// is swizzle-correct (rule #21: linear dest + inverse-swz source + swz read).
__global__ __launch_bounds__(256)
void k_wconv(const float* __restrict__ Wv, const float* __restrict__ Wu,
             uint16_t* __restrict__ Wb) {
  __shared__ float lt[32 * 130];
  const int tid = threadIdx.x;
  const int ks  = blockIdx.x;   // 0..15: m-block of 32 = one k-step group
  const int g   = blockIdx.y;   // 0..1
  const float* src = g ? Wu : Wv;
  #pragma unroll
  for (int j = 0; j < 16; ++j) {
    int idx = j * 256 + tid;        // [32 m][128 l], l fastest -> coalesced
    int m = idx >> 7, l = idx & 127;
    lt[m * 130 + l] = src[(ks * 32 + m) * 128 + l];
  }
  __syncthreads();
  const int l = tid >> 1, half = tid & 1;
  const int key = (l >> 1) & 3;
  uint16_t outv[16];
  #pragma unroll
  for (int i = 0; i < 16; ++i) {
    int cp   = half * 2 + (i >> 3);       // stored chunk index
    int e    = i & 7;
    int mloc = ((cp ^ key) << 3) | e;     // source m within the 32-row group
    outv[i] = (uint16_t)f2bf(lt[mloc * 130 + l]);
  }
  uint16_t* dst = Wb + g * 65536 + l * 512 + ks * 32 + half * 16;
  *(uint4*)dst       = ((const uint4*)outv)[0];
  *(uint4*)(dst + 8) = ((const uint4*)outv)[1];
}

// K2: fused gates GEMM (bf16 MFMA) + logits + e_t + tile-local pooling.
// grid (NTILE, B_), 256 threads = 4 waves; wave wv owns L-quarter wv*32..+31
// and ALL 64 t-rows. 4-deep W LDS pipeline + 3-deep H reg pipeline, raw
// s_barrier, counted waits (no vmcnt(0) in the loop).
__global__ __launch_bounds__(256, 2)
void k_gates_pool(const float* __restrict__ H, const uint16_t* __restrict__ Wb,
                  const float* __restrict__ bv, const float* __restrict__ bu,
                  const float* __restrict__ Wa, const float* __restrict__ ba,
                  float* __restrict__ At, float* __restrict__ Ew,
                  float* __restrict__ Sums, float* __restrict__ Mp8) {
  __shared__ __align__(16) uint16_t smW[4 * 8192];  // 4 bufs x [2g][128l][4c][8e] = 64 KB
  __shared__ __align__(16) uint16_t smH[2 * 2048];  // 2 bufs x [64t][4c][8e]     = 8 KB
  __shared__ float esm_p[4][64];
  __shared__ float esm[64];
  const int tid  = threadIdx.x;
  const int lane = tid & 63;
  const int wv   = tid >> 6;
  const int lc   = lane & 15;
  const int kq   = lane >> 4;
  const int tile  = blockIdx.x;
  const int b     = blockIdx.y;
  const int tbase = tile * 64;

  // ---- W staging pointers (linear: source is pre-swizzled)
  const uint16_t* wsrc[4];
  uint16_t* wdst[4];
  #pragma unroll
  for (int j = 0; j < 4; ++j) {
    int i = j * 256 + tid;    // [g][l][c]
    wsrc[j] = Wb + (i >> 9) * 65536 + ((i >> 2) & 127) * 512 + (i & 3) * 8;
    wdst[j] = smW + i * 8;
  }
  // ---- H staging: row ht, 8-float chunk hcc (swizzled ds_write)
  const int ht  = tid >> 2;
  const int hcc = tid & 3;
  const int gts = tbase + ht;
  const float* hsrc = H + ((size_t)b * T_ + (gts < T_ ? gts : T_ - 1)) * M_ + hcc * 8;
  uint16_t* hdst = smH + ht * 32 + ((hcc ^ ((ht >> 1) & 3)) << 3);

  // ---- MFMA frag read offsets (swizzled)
  int hoff[4], woff[2];
  #pragma unroll
  for (int tf = 0; tf < 4; ++tf) {
    int hr = tf * 16 + lc;
    hoff[tf] = hr * 32 + ((kq ^ ((hr >> 1) & 3)) << 3);
  }
  #pragma unroll
  for (int lf = 0; lf < 2; ++lf) {
    int lr = wv * 32 + lf * 16 + lc;
    woff[lf] = lr * 32 + ((kq ^ ((lr >> 1) & 3)) << 3);
  }

  f32x4 accV[4][2], accU[4][2];
  #pragma unroll
  for (int tf = 0; tf < 4; ++tf)
    #pragma unroll
    for (int lf = 0; lf < 2; ++lf) {
      accV[tf][lf] = f32x4{0.f, 0.f, 0.f, 0.f};
      accU[tf][lf] = f32x4{0.f, 0.f, 0.f, 0.f};
    }

  f32x4 hreg[3][2];
  auto packw = [&](const f32x4* h, uint16_t* d) {
    uint4 u;
    u.x = f2bf(h[0][0]) | (f2bf(h[0][1]) << 16);
    u.y = f2bf(h[0][2]) | (f2bf(h[0][3]) << 16);
    u.z = f2bf(h[1][0]) | (f2bf(h[1][1]) << 16);
    u.w = f2bf(h[1][2]) | (f2bf(h[1][3]) << 16);
    *(uint4*)d = u;
  };

  // ---- prologue: issue W0,H0, W1,W2, H1,H2; write H0 to LDS; barrier
  #pragma unroll
  for (int j = 0; j < 4; ++j) gld_lds16(wsrc[j], wdst[j]);
  hreg[0][0] = *(const f32x4*)(hsrc);
  hreg[0][1] = *(const f32x4*)(hsrc + 4);
  #pragma unroll
  for (int j = 0; j < 4; ++j) gld_lds16(wsrc[j] + 32, wdst[j] + 8192);
  #pragma unroll
  for (int j = 0; j < 4; ++j) gld_lds16(wsrc[j] + 64, wdst[j] + 16384);
  hreg[1][0] = *(const f32x4*)(hsrc + 32);
  hreg[1][1] = *(const f32x4*)(hsrc + 36);
  hreg[2][0] = *(const f32x4*)(hsrc + 64);
  hreg[2][1] = *(const f32x4*)(hsrc + 68);
  packw(hreg[0], hdst);                       // consumes H0 -> drains W0 (vmcnt)
  asm volatile("s_waitcnt lgkmcnt(0)" ::: "memory");
  __builtin_amdgcn_s_barrier();
  __builtin_amdgcn_sched_barrier(0);

  // ---- main loop: K = 512, 32 per step, fully unrolled
  #pragma unroll
  for (int s = 0; s < 16; ++s) {
    if (s + 3 < 16) {
      #pragma unroll
      for (int j = 0; j < 4; ++j)
        gld_lds16(wsrc[j] + (s + 3) * 32, wdst[j] + ((s + 3) & 3) * 8192);
      hreg[s % 3][0] = *(const f32x4*)(hsrc + (s + 3) * 32);
      hreg[s % 3][1] = *(const f32x4*)(hsrc + (s + 3) * 32 + 4);
    }
    const uint16_t* Wp = smW + (s & 3) * 8192;
    const uint16_t* Hb = smH + (s & 1) * 2048;
    bf16x8 a[4];
    #pragma unroll
    for (int tf = 0; tf < 4; ++tf) a[tf] = *(const bf16x8*)&Hb[hoff[tf]];
    #pragma unroll
    for (int lf = 0; lf < 2; ++lf) {
      bf16x8 bw = *(const bf16x8*)&Wp[woff[lf]];
      bf16x8 uw = *(const bf16x8*)&Wp[4096 + woff[lf]];
      #pragma unroll
      for (int tf = 0; tf < 4; ++tf) {
        accV[tf][lf] = __builtin_amdgcn_mfma_f32_16x16x32_bf16(a[tf], bw, accV[tf][lf], 0, 0, 0);
        accU[tf][lf] = __builtin_amdgcn_mfma_f32_16x16x32_bf16(a[tf], uw, accU[tf][lf], 0, 0, 0);
      }
    }
    if (s + 1 < 16)   // consume H(s+1) regs -> implicit vmcnt drains W(s+1)
      packw(hreg[(s + 1) % 3], hdst + ((s + 1) & 1) * 2048);
    if (s < 15) {
      asm volatile("s_waitcnt lgkmcnt(0)" ::: "memory");
      __builtin_amdgcn_s_barrier();
      __builtin_amdgcn_sched_barrier(0);
    }
  }

  // ---- epilogue: gated logit partials (this wave's 32 L-cols), cross-wave reduce
  float wa2[2], bvv[2], buu[2];
  #pragma unroll
  for (int lf = 0; lf < 2; ++lf) {
    int l = wv * 32 + lf * 16 + lc;
    wa2[lf] = Wa[l]; bvv[lf] = bv[l]; buu[lf] = bu[l];
  }
  const float ba0 = ba[0];
  #pragma unroll
  for (int tf = 0; tf < 4; ++tf) {
    float part[4] = {0.f, 0.f, 0.f, 0.f};
    #pragma unroll
    for (int lf = 0; lf < 2; ++lf) {
      #pragma unroll
      for (int r = 0; r < 4; ++r) {
        float xv = accV[tf][lf][r] + bvv[lf];
        float xu = accU[tf][lf][r] + buu[lf];
        xv = fminf(fmaxf(xv, -30.f), 30.f);
        float e  = __expf(2.f * xv);
        float th = (e - 1.f) * __builtin_amdgcn_rcpf(e + 1.f);
        float sg = __builtin_amdgcn_rcpf(1.f + __expf(-xu));
        part[r] += th * sg * wa2[lf];
      }
    }
    #pragma unroll
    for (int r = 0; r < 4; ++r) {
      part[r] += __shfl_xor(part[r], 1);
      part[r] += __shfl_xor(part[r], 2);
      part[r] += __shfl_xor(part[r], 4);
      part[r] += __shfl_xor(part[r], 8);
    }
    if (lc == 0) {
      #pragma unroll
      for (int r = 0; r < 4; ++r) esm_p[wv][tf * 16 + kq * 4 + r] = part[r];
    }
  }
  __syncthreads();
  if (tid < 64) {
    float logit = esm_p[0][tid] + esm_p[1][tid] + esm_p[2][tid] + esm_p[3][tid] + ba0;
    int gt = tbase + tid;
    float e = 0.f;
    if (gt < T_) {
      At[b * T_ + gt] = logit;
      e = __expf(logit);                 // no max-subtraction: |logit| <~ 5.5
      Ew[(b << 9) + gt] = e;
    }
    esm[tid] = e;
    float v = e;
    v += __shfl_xor(v, 1);  v += __shfl_xor(v, 2);  v += __shfl_xor(v, 4);
    v += __shfl_xor(v, 8);  v += __shfl_xor(v, 16); v += __shfl_xor(v, 32);
    if (tid == 0) Sums[b * NTILE + tile] = v;
  }
  __syncthreads();

  // ---- pooling: P[m] = sum_t e_t * H[t,m] for this tile (H is L2/L3-hot)
  const int tmax = (T_ - tbase < 64) ? (T_ - tbase) : 64;
  const float2* hp = (const float2*)(H + ((size_t)b * T_ + tbase) * M_) + tid;
  float a0 = 0.f, a1 = 0.f;
  #pragma unroll 4
  for (int t = 0; t < tmax; ++t) {
    float e = esm[t];
    float2 h2 = hp[(size_t)t * 256];
    a0 += e * h2.x;
    a1 += e * h2.y;
  }
  float2* mp = (float2*)(Mp8 + ((size_t)(b * NTILE + tile) << 9));
  mp[tid] = make_float2(a0, a1);
}

// K3: per-bag finish: sum-e, A_sm normalize, Mpool reduce, head GEMV
__global__ __launch_bounds__(256)
void k_finish(const float* __restrict__ Ew, const float* __restrict__ Sums,
              const float* __restrict__ Mp8, const float* __restrict__ Wc,
              const float* __restrict__ bc, float* __restrict__ out,
              float* __restrict__ Asm) {
  __shared__ float rs[8];
  const int b = blockIdx.x;
  const int tid = threadIdx.x;
  float se = 0.f;
  #pragma unroll
  for (int j = 0; j < NTILE; ++j) se += Sums[b * NTILE + j];
  const float inv = 1.f / se;
  for (int t = tid; t < T_; t += 256) Asm[b * T_ + t] = Ew[(b << 9) + t] * inv;
  float mp0 = 0.f, mp1 = 0.f;
  #pragma unroll
  for (int j = 0; j < NTILE; ++j) {
    float2 v = ((const float2*)(Mp8 + ((size_t)(b * NTILE + j) << 9)))[tid];
    mp0 += v.x; mp1 += v.y;
  }
  mp0 *= inv; mp1 *= inv;
  float4 w = ((const float4*)Wc)[tid];    // Wc[2tid][0..1], Wc[2tid+1][0..1]
  float c0 = mp0 * w.x + mp1 * w.z;
  float c1 = mp0 * w.y + mp1 * w.w;
  #pragma unroll
  for (int m = 32; m; m >>= 1) { c0 += __shfl_xor(c0, m); c1 += __shfl_xor(c1, m); }
  const int lane = tid & 63, wv = tid >> 6;
  if (lane == 0) { rs[wv] = c0; rs[4 + wv] = c1; }
  __syncthreads();
  if (tid == 0) out[b * 2]     = rs[0] + rs[1] + rs[2] + rs[3] + bc[0];
  if (tid == 1) out[b * 2 + 1] = rs[4] + rs[5] + rs[6] + rs[7] + bc[1];
}

extern "C" void kernel_launch(void* const* d_in, const int* in_sizes, int n_in,
                              void* d_out, int out_size, void* d_ws, size_t ws_size,
                              hipStream_t stream) {
  const float* H  = (const float*)d_in[0];
  const float* Wv = (const float*)d_in[1];
  const float* bv = (const float*)d_in[2];
  const float* Wu = (const float*)d_in[3];
  const float* bu = (const float*)d_in[4];
  const float* Wa = (const float*)d_in[5];
  const float* ba = (const float*)d_in[6];
  const float* Wc = (const float*)d_in[7];
  const float* bc = (const float*)d_in[8];

  float* out = (float*)d_out;                   // [128,2]
  float* Asm = out + 256;                       // [128,500] A_after_sftmx
  float* At  = out + 256 + 64000;               // [128,500] A_t (logits)

  uint16_t* Wb = (uint16_t*)d_ws;                        // 2 x [128][512] bf16 = 256 KB
  float* Ew   = (float*)((char*)d_ws + 262144);          // [128][512] f32 = 256 KB
  float* Sums = (float*)((char*)d_ws + 524288);          // [128][8]       = 4 KB
  float* Mp8  = (float*)((char*)d_ws + 528384);          // [128][8][512]  = 2 MB

  hipLaunchKernelGGL(k_wconv,      dim3(16, 2),     dim3(256), 0, stream, Wv, Wu, Wb);
  hipLaunchKernelGGL(k_gates_pool, dim3(NTILE, B_), dim3(256), 0, stream,
                     H, Wb, bv, bu, Wa, ba, At, Ew, Sums, Mp8);
  hipLaunchKernelGGL(k_finish,     dim3(B_),        dim3(256), 0, stream,
                     Ew, Sums, Mp8, Wc, bc, out, Asm);
}